// Round 1
// baseline (346.138 us; speedup 1.0000x reference)
//
#include <hip/hip_runtime.h>
#include <hip/hip_bf16.h>
#include <cstdint>
#include <cstddef>

// Problem constants (match reference)
#define B_    16
#define CIN   960
#define HH    56
#define WW_   56
#define HP    58
#define WP    58
#define GG    2
#define COUT  96
#define NK_   5
#define PIX_PAD (HP * WP)   // 3364
#define PIX_OUT (HH * WW_)  // 3136

// Workspace layout (in floats)
#define WEFF_OFF 0
#define BIAS_OFF (COUT * CIN)            // 92160
#define Y_OFF    92288                   // 92160+96 rounded up to x64
// total ws floats = 92288 + 16*96*3364 = 5,258,624  (~20.1 MiB)

// ---------------------------------------------------------------------------
// K0a: weff[c][o] = proj_w[o][c] * (scale[c] + 1e-5)   (transposed for staging)
__global__ void prep_weff(const float* __restrict__ pw, const float* __restrict__ sc,
                          float* __restrict__ weff) {
    int idx = blockIdx.x * 256 + threadIdx.x;   // idx = c*96 + o
    if (idx >= COUT * CIN) return;
    int c = idx / COUT;
    int o = idx - c * COUT;
    weff[idx] = pw[o * CIN + c] * (sc[c] + 1e-5f);
}

// K0b: bias_o[o] = sum_c proj_w[o][c] * local_bias[c]
__global__ void prep_bias(const float* __restrict__ pw, const float* __restrict__ bi,
                          float* __restrict__ bias) {
    int o = threadIdx.x;
    if (o >= COUT) return;
    float s = 0.f;
    for (int c = 0; c < CIN; ++c) s += pw[o * CIN + c] * bi[c];
    bias[o] = s;
}

// ---------------------------------------------------------------------------
// K1: y[b, o, i, j] = bias_o + sum_c weff[c][o] * xp[b, c, i, j]
//   on the edge-padded 58x58 grid: xp[i][j] = x[clamp(i-1), clamp(j-1)]
// Tile: 64 pixels x 96 outputs per block of 256 threads.
// Thread (tx = pixel 0..63, ty = o-group 0..3) owns 24 fp32 accumulators.
__global__ void conv_pad(const float* __restrict__ x, const float* __restrict__ weff,
                         const float* __restrict__ bias, float* __restrict__ y) {
    const int tid = threadIdx.x;
    const int tx = tid & 63;
    const int ty = tid >> 6;
    const int b = blockIdx.y;
    const int pix = blockIdx.x * 64 + tx;
    const bool val = pix < PIX_PAD;

    int i = pix / WP;
    int j = pix - i * WP;
    int r  = min(HH - 1, max(0, i - 1));
    int cl = min(WW_ - 1, max(0, j - 1));
    const size_t xoff = val ? ((size_t)r * WW_ + cl) : 0;
    const float* xb = x + (size_t)b * CIN * PIX_OUT;

    __shared__ float wch[32][COUT];   // 12 KiB
    __shared__ float xch[32][64];     // 8 KiB

    float acc[24];
#pragma unroll
    for (int u = 0; u < 24; ++u) acc[u] = 0.f;

    for (int c0 = 0; c0 < CIN; c0 += 32) {
        // stage weights: 32*96 = 3072 floats, 12 per thread, coalesced
#pragma unroll
        for (int t = 0; t < 12; ++t) {
            int s = tid + t * 256;
            ((float*)wch)[s] = weff[(size_t)c0 * COUT + s];
        }
        // stage x tile: channel ch = ty + 4*it for this thread's pixel
#pragma unroll
        for (int it = 0; it < 8; ++it) {
            int ch = ty + 4 * it;
            xch[ch][tx] = xb[(size_t)(c0 + ch) * PIX_OUT + xoff];
        }
        __syncthreads();
#pragma unroll 8
        for (int cc = 0; cc < 32; ++cc) {
            const float xv = xch[cc][tx];
#pragma unroll
            for (int og = 0; og < 6; ++og) {
                const float4 wv = *(const float4*)&wch[cc][ty * 24 + og * 4];
                acc[og * 4 + 0] = fmaf(xv, wv.x, acc[og * 4 + 0]);
                acc[og * 4 + 1] = fmaf(xv, wv.y, acc[og * 4 + 1]);
                acc[og * 4 + 2] = fmaf(xv, wv.z, acc[og * 4 + 2]);
                acc[og * 4 + 3] = fmaf(xv, wv.w, acc[og * 4 + 3]);
            }
        }
        __syncthreads();
    }

    if (val) {
#pragma unroll
        for (int u = 0; u < 24; ++u) {
            int o = ty * 24 + u;
            y[((size_t)b * COUT + o) * PIX_PAD + pix] = acc[u] + bias[o];
        }
    }
}

// ---------------------------------------------------------------------------
// Antialiased triangle resize weights for 58 -> 56 (jax.image.resize bilinear,
// antialias=True): sf = (o+0.5)*58/56 - 0.5, kernel_scale = 58/56,
// w_i = relu(1 - |sf - i| * 56/58) for i in [0,58), column-normalized.
__device__ __forceinline__ void rweights(int o, int* idx, float* wt) {
    const float ratio = 58.0f / 56.0f;
    const float kinv  = 56.0f / 58.0f;
    const float sf = ((float)o + 0.5f) * ratio - 0.5f;
    const int f0 = (int)floorf(sf);
    float sum = 0.f;
#pragma unroll
    for (int t = 0; t < 4; ++t) {
        int i = f0 - 1 + t;
        float w = fmaxf(1.0f - fabsf(sf - (float)i) * kinv, 0.0f);
        if (i < 0 || i > HP - 1) w = 0.0f;   // out-of-range taps excluded pre-normalization
        idx[t] = min(HP - 1, max(0, i));
        wt[t] = w;
        sum += w;
    }
    const float inv = 1.0f / sum;
#pragma unroll
    for (int t = 0; t < 4; ++t) wt[t] *= inv;
}

// ---------------------------------------------------------------------------
// K2: out[b,co,h,w] = alpha * (x1+x2+x3)/3 + (1-alpha) * resize(y)[b,co,h,w]
// One block per 256 pixels of one (b, co) plane -> shift tables are block-uniform.
__global__ void finalize(const float* __restrict__ x, const int* __restrict__ pad_hv,
                         const int* __restrict__ idt, const float* __restrict__ y,
                         const float* __restrict__ alpha_p, float* __restrict__ out) {
    const int bc = blockIdx.y;      // b*96 + co
    const int co = bc % COUT;
    const int b  = bc / COUT;
    const int p = blockIdx.x * 256 + threadIdx.x;
    if (p >= PIX_OUT) return;
    const int h = p / WW_;
    const int w = p - h * WW_;
    const float alpha = alpha_p[0];

    const float* xb = x + (size_t)b * CIN * PIX_OUT;

    float accg = 0.f;
#pragma unroll
    for (int g = 0; g < GG; ++g) {
#pragma unroll
        for (int k = 0; k < NK_; ++k) {
            const int slot = co * NK_ + k;
            const int ic = g * (COUT * NK_) + slot;
            const float* xc = xb + (size_t)ic * PIX_OUT;
            const int sh  = pad_hv[slot * 4 + g];        // horizontal (w) shift
            const int sv  = pad_hv[slot * 4 + 2 + g];    // vertical (h) shift
            const int idm = idt[slot * 2 + g];

            // horizontal: valid iff w+sh in [-1, 56]; col edge-clamped to [0,55]
            const int jw = w + sh;
            if (jw >= -1 && jw <= WW_)
                accg += xc[h * WW_ + min(WW_ - 1, max(0, jw))];
            // vertical: valid iff h+sv in [-1, 56]; row edge-clamped
            const int ih2 = h + sv;
            if (ih2 >= -1 && ih2 <= HH)
                accg += xc[min(HH - 1, max(0, ih2)) * WW_ + w];
            // identity slots
            if (idm >= 0)
                accg += xc[h * WW_ + w];
        }
    }

    // separable antialiased resize of y (up to 3 nonzero taps per dim; 4 computed)
    int ihx[4], iwx[4];
    float whx[4], wwx[4];
    rweights(h, ihx, whx);
    rweights(w, iwx, wwx);
    const float* yb = y + (size_t)bc * PIX_PAD;
    float accl = 0.f;
#pragma unroll
    for (int a = 0; a < 4; ++a) {
        float rs = 0.f;
#pragma unroll
        for (int t = 0; t < 4; ++t)
            rs = fmaf(wwx[t], yb[ihx[a] * WP + iwx[t]], rs);
        accl = fmaf(whx[a], rs, accl);
    }

    out[(size_t)bc * PIX_OUT + p] = alpha * accg * (1.0f / 3.0f) + (1.0f - alpha) * accl;
}

// ---------------------------------------------------------------------------
extern "C" void kernel_launch(void* const* d_in, const int* in_sizes, int n_in,
                              void* d_out, int out_size, void* d_ws, size_t ws_size,
                              hipStream_t stream) {
    const float* x      = (const float*)d_in[0];
    const int*   pad_hv = (const int*)d_in[1];
    const int*   idt    = (const int*)d_in[2];
    const float* lsc    = (const float*)d_in[3];
    const float* lbi    = (const float*)d_in[4];
    const float* pw     = (const float*)d_in[5];
    const float* alpha  = (const float*)d_in[6];
    float* out = (float*)d_out;

    float* ws   = (float*)d_ws;
    float* weff = ws + WEFF_OFF;
    float* bias = ws + BIAS_OFF;
    float* y    = ws + Y_OFF;
    // requires ws_size >= (92288 + 16*96*3364)*4 ~= 20.1 MiB

    prep_weff<<<(COUT * CIN + 255) / 256, 256, 0, stream>>>(pw, lsc, weff);
    prep_bias<<<1, 128, 0, stream>>>(pw, lbi, bias);
    conv_pad<<<dim3((PIX_PAD + 63) / 64, B_), 256, 0, stream>>>(x, weff, bias, y);
    finalize<<<dim3((PIX_OUT + 255) / 256, B_ * COUT), 256, 0, stream>>>(
        x, pad_hv, idt, y, alpha, out);
}

// Round 2
// 228.313 us; speedup vs baseline: 1.5161x; 1.5161x over previous
//
#include <hip/hip_runtime.h>
#include <hip/hip_bf16.h>
#include <cstdint>
#include <cstddef>

// Problem constants (match reference)
#define B_    16
#define CIN   960
#define HH    56
#define WW_   56
#define HP    58
#define WP    58
#define GG    2
#define COUT  96
#define NK_   5
#define PIX_PAD (HP * WP)   // 3364
#define PIX_OUT (HH * WW_)  // 3136

// Workspace layout (in floats)
#define WB_OFF   0                       // bf16 weights [96][960] -> 184320 B = 46080 floats
#define BIAS_OFF 46080
#define Y_OFF    46208                   // 64-aligned
// total floats = 46208 + 16*96*3364 = 5,213,312  (~19.9 MiB)

typedef __attribute__((ext_vector_type(8))) short bf16x8;
typedef __attribute__((ext_vector_type(4))) float f32x4;

// fp32 -> bf16 (RNE) bit trick, no NaN path needed for this data
__device__ __forceinline__ short f2b(float f) {
    union { float f; unsigned u; } c; c.f = f;
    unsigned r = (c.u + 0x7FFFu + ((c.u >> 16) & 1u)) >> 16;
    return (short)r;
}

// ---------------------------------------------------------------------------
// K0a: wb[o][c] = bf16( proj_w[o][c] * (scale[c] + 1e-5) )   row-major [96][960]
__global__ void prep_wb(const float* __restrict__ pw, const float* __restrict__ sc,
                        short* __restrict__ wb) {
    int idx = blockIdx.x * 256 + threadIdx.x;   // idx = o*960 + c
    if (idx >= COUT * CIN) return;
    int c = idx % CIN;
    wb[idx] = f2b(pw[idx] * (sc[c] + 1e-5f));
}

// K0b: bias_o[o] = sum_c proj_w[o][c] * local_bias[c]
__global__ void prep_bias(const float* __restrict__ pw, const float* __restrict__ bi,
                          float* __restrict__ bias) {
    int o = threadIdx.x;
    if (o >= COUT) return;
    float s = 0.f;
    for (int c = 0; c < CIN; ++c) s += pw[o * CIN + c] * bi[c];
    bias[o] = s;
}

// ---------------------------------------------------------------------------
// K1: y[b, o, pix] = bias_o + sum_c W[o][c] * xp[b, c, pix]  (58x58 padded grid)
// MFMA GEMM: M=96 (6 frags), N=64 px per block (16 px per wave), K=960.
// Block = 256 threads = 4 waves. X chunk (32ch x 64px) staged bf16 in LDS
// with XOR swizzle; W fragments read from global bf16 (L2-resident).
__global__ __launch_bounds__(256)
void conv_mfma(const float* __restrict__ x, const short* __restrict__ wb,
               const float* __restrict__ bias, float* __restrict__ y) {
    const int tid  = threadIdx.x;
    const int lane = tid & 63;
    const int wv   = tid >> 6;          // wave id (also staging k-block)
    const int b    = blockIdx.y;
    const int blk  = blockIdx.x;

    // ---- staging role: this thread gathers pixel `lane` of the tile
    int pix_s = blk * 64 + lane;
    if (pix_s > PIX_PAD - 1) pix_s = PIX_PAD - 1;
    {
    }
    const int si = pix_s / WP;
    const int sj = pix_s - si * WP;
    const int sr = min(HH - 1, max(0, si - 1));
    const int sc_ = min(WW_ - 1, max(0, sj - 1));
    const float* xb = x + (size_t)b * CIN * PIX_OUT + ((size_t)sr * WW_ + sc_);

    // ---- compute role: wave wv covers tile columns [wv*16, wv*16+16)
    const int cpx = wv * 16 + (lane & 15);   // local pixel col (0..63)
    const int kb  = lane >> 4;               // k-block 0..3 (8 k each)

    __shared__ short xs[64 * 32];            // 4 KiB, swizzled

    // swizzled byte offsets: (px*64 + kb*16) ^ ((px&7)<<4)
    char* xs_wp = (char*)xs + (((lane * 64 + wv * 16) ^ ((lane & 7) << 4)));
    const char* xs_rp = (const char*)xs + (((cpx * 64 + kb * 16) ^ ((cpx & 7) << 4)));

    f32x4 acc[6];
#pragma unroll
    for (int f = 0; f < 6; ++f) acc[f] = (f32x4){0.f, 0.f, 0.f, 0.f};

    // prefetch first chunk: channels wv*8 .. wv*8+7 at this thread's pixel
    float v[8];
#pragma unroll
    for (int t = 0; t < 8; ++t)
        v[t] = xb[(size_t)(wv * 8 + t) * PIX_OUT];

    for (int c0 = 0; c0 < CIN; c0 += 32) {
        bf16x8 pk;
#pragma unroll
        for (int t = 0; t < 8; ++t) pk[t] = f2b(v[t]);
        __syncthreads();                      // previous chunk's reads done
        *(bf16x8*)xs_wp = pk;                 // ds_write_b128 (swizzled)
        __syncthreads();                      // chunk visible

        if (c0 + 32 < CIN) {                  // prefetch next chunk (hides HBM latency)
#pragma unroll
            for (int t = 0; t < 8; ++t)
                v[t] = xb[(size_t)(c0 + 32 + wv * 8 + t) * PIX_OUT];
        }

        const bf16x8 bfrag = *(const bf16x8*)xs_rp;  // ds_read_b128 (swizzled)
#pragma unroll
        for (int f = 0; f < 6; ++f) {
            const bf16x8 afrag = *(const bf16x8*)(wb + ((size_t)(f * 16 + (lane & 15)) * CIN + c0 + kb * 8));
            acc[f] = __builtin_amdgcn_mfma_f32_16x16x32_bf16(afrag, bfrag, acc[f], 0, 0, 0);
        }
    }

    // ---- epilogue: C/D layout col = lane&15, row = (lane>>4)*4 + r
    const int px_c = blk * 64 + cpx;
    if (px_c < PIX_PAD) {
        float* yb = y + (size_t)b * COUT * PIX_PAD + px_c;
#pragma unroll
        for (int f = 0; f < 6; ++f) {
            const int o0 = f * 16 + (lane >> 4) * 4;
#pragma unroll
            for (int r = 0; r < 4; ++r) {
                const int o = o0 + r;
                yb[(size_t)o * PIX_PAD] = acc[f][r] + bias[o];
            }
        }
    }
}

// ---------------------------------------------------------------------------
// Antialiased triangle resize weights for 58 -> 56 (jax.image.resize bilinear,
// antialias=True): sf = (o+0.5)*58/56 - 0.5, w_i = relu(1 - |sf-i|*56/58),
// column-normalized.
__device__ __forceinline__ void rweights(int o, int* idx, float* wt) {
    const float ratio = 58.0f / 56.0f;
    const float kinv  = 56.0f / 58.0f;
    const float sf = ((float)o + 0.5f) * ratio - 0.5f;
    const int f0 = (int)floorf(sf);
    float sum = 0.f;
#pragma unroll
    for (int t = 0; t < 4; ++t) {
        int i = f0 - 1 + t;
        float w = fmaxf(1.0f - fabsf(sf - (float)i) * kinv, 0.0f);
        if (i < 0 || i > HP - 1) w = 0.0f;
        idx[t] = min(HP - 1, max(0, i));
        wt[t] = w;
        sum += w;
    }
    const float inv = 1.0f / sum;
#pragma unroll
    for (int t = 0; t < 4; ++t) wt[t] *= inv;
}

// ---------------------------------------------------------------------------
// K2: out = alpha*(x1+x2+x3)/3 + (1-alpha)*resize(y)
__global__ void finalize(const float* __restrict__ x, const int* __restrict__ pad_hv,
                         const int* __restrict__ idt, const float* __restrict__ y,
                         const float* __restrict__ alpha_p, float* __restrict__ out) {
    const int bc = blockIdx.y;      // b*96 + co
    const int co = bc % COUT;
    const int b  = bc / COUT;
    const int p = blockIdx.x * 256 + threadIdx.x;
    if (p >= PIX_OUT) return;
    const int h = p / WW_;
    const int w = p - h * WW_;
    const float alpha = alpha_p[0];

    const float* xb = x + (size_t)b * CIN * PIX_OUT;

    float accg = 0.f;
#pragma unroll
    for (int g = 0; g < GG; ++g) {
#pragma unroll
        for (int k = 0; k < NK_; ++k) {
            const int slot = co * NK_ + k;
            const int ic = g * (COUT * NK_) + slot;
            const float* xc = xb + (size_t)ic * PIX_OUT;
            const int sh  = pad_hv[slot * 4 + g];        // horizontal (w) shift
            const int sv  = pad_hv[slot * 4 + 2 + g];    // vertical (h) shift
            const int idm = idt[slot * 2 + g];

            const int jw = w + sh;
            if (jw >= -1 && jw <= WW_)
                accg += xc[h * WW_ + min(WW_ - 1, max(0, jw))];
            const int ih2 = h + sv;
            if (ih2 >= -1 && ih2 <= HH)
                accg += xc[min(HH - 1, max(0, ih2)) * WW_ + w];
            if (idm >= 0)
                accg += xc[h * WW_ + w];
        }
    }

    int ihx[4], iwx[4];
    float whx[4], wwx[4];
    rweights(h, ihx, whx);
    rweights(w, iwx, wwx);
    const float* yb = y + (size_t)bc * PIX_PAD;
    float accl = 0.f;
#pragma unroll
    for (int a = 0; a < 4; ++a) {
        float rs = 0.f;
#pragma unroll
        for (int t = 0; t < 4; ++t)
            rs = fmaf(wwx[t], yb[ihx[a] * WP + iwx[t]], rs);
        accl = fmaf(whx[a], rs, accl);
    }

    out[(size_t)bc * PIX_OUT + p] = alpha * accg * (1.0f / 3.0f) + (1.0f - alpha) * accl;
}

// ---------------------------------------------------------------------------
extern "C" void kernel_launch(void* const* d_in, const int* in_sizes, int n_in,
                              void* d_out, int out_size, void* d_ws, size_t ws_size,
                              hipStream_t stream) {
    const float* x      = (const float*)d_in[0];
    const int*   pad_hv = (const int*)d_in[1];
    const int*   idt    = (const int*)d_in[2];
    const float* lsc    = (const float*)d_in[3];
    const float* lbi    = (const float*)d_in[4];
    const float* pw     = (const float*)d_in[5];
    const float* alpha  = (const float*)d_in[6];
    float* out = (float*)d_out;

    float* ws   = (float*)d_ws;
    short* wb   = (short*)(ws + WB_OFF);
    float* bias = ws + BIAS_OFF;
    float* y    = ws + Y_OFF;

    prep_wb<<<(COUT * CIN + 255) / 256, 256, 0, stream>>>(pw, lsc, wb);
    prep_bias<<<1, 128, 0, stream>>>(pw, lbi, bias);
    conv_mfma<<<dim3((PIX_PAD + 63) / 64, B_), 256, 0, stream>>>(x, wb, bias, y);
    finalize<<<dim3((PIX_OUT + 255) / 256, B_ * COUT), 256, 0, stream>>>(
        x, pad_hv, idt, y, alpha, out);
}

// Round 3
// 196.721 us; speedup vs baseline: 1.7595x; 1.1606x over previous
//
#include <hip/hip_runtime.h>
#include <hip/hip_bf16.h>
#include <cstdint>
#include <cstddef>

// Problem constants (match reference)
#define B_    16
#define CIN   960
#define HH    56
#define WW_   56
#define HP    58
#define WP    58
#define GG    2
#define COUT  96
#define NK_   5
#define PIX_PAD (HP * WP)   // 3364
#define PIX_OUT (HH * WW_)  // 3136

// Workspace layout (in floats)
#define WB_OFF   0                       // bf16 weights [96][960] = 46080 shorts = 23040 floats... keep slot generous
#define BIAS_OFF 46080
#define Y_OFF    46208                   // y56: 16*96*3136 floats = 4,816,896
// total floats = 46208 + 4,816,896 ~= 18.6 MiB

typedef __attribute__((ext_vector_type(8))) short bf16x8;
typedef __attribute__((ext_vector_type(4))) float f32x4;

// fp32 -> bf16 (RNE) bit trick
__device__ __forceinline__ short f2b(float f) {
    union { float f; unsigned u; } c; c.f = f;
    unsigned r = (c.u + 0x7FFFu + ((c.u >> 16) & 1u)) >> 16;
    return (short)r;
}

// ---------------------------------------------------------------------------
// K0a: wb[o][c] = bf16( proj_w[o][c] * (scale[c] + 1e-5) )   row-major [96][960]
__global__ void prep_wb(const float* __restrict__ pw, const float* __restrict__ sc,
                        short* __restrict__ wb) {
    int idx = blockIdx.x * 256 + threadIdx.x;   // idx = o*960 + c
    if (idx >= COUT * CIN) return;
    int c = idx % CIN;
    wb[idx] = f2b(pw[idx] * (sc[c] + 1e-5f));
}

// K0b: bias_o[o] = sum_c proj_w[o][c] * local_bias[c]
__global__ void prep_bias(const float* __restrict__ pw, const float* __restrict__ bi,
                          float* __restrict__ bias) {
    int o = threadIdx.x;
    if (o >= COUT) return;
    float s = 0.f;
    for (int c = 0; c < CIN; ++c) s += pw[o * CIN + c] * bi[c];
    bias[o] = s;
}

// ---------------------------------------------------------------------------
// K1: y56[b, o, p] = bias_o + sum_c W[o][c] * x[b, c, p]   -- PURE GEMM,
// M=96, K=960, N=16*3136. Block = 128 thr (2 waves) handles 32 px x 96 out.
// Grid = 98*16 = 1568 blocks -> whole grid co-resident (~6 blocks/CU).
// LDS: double-buffered 32px x 32ch bf16 chunks, XOR-swizzled, ONE barrier/chunk.
// Register prefetch 2 chunks deep (static v0/v1, even/odd unrolled bodies).
__global__ __launch_bounds__(128)
void conv_mfma(const float* __restrict__ x, const short* __restrict__ wb,
               const float* __restrict__ bias, float* __restrict__ y) {
    const int tid  = threadIdx.x;
    const int lane = tid & 63;
    const int wv   = tid >> 6;          // wave 0..1
    const int b    = blockIdx.y;
    const int px0  = blockIdx.x * 32;

    // staging role: pixel sp = tid&31, channel group sg = tid>>5 (0..3)
    const int sp = tid & 31;
    const int sg = tid >> 5;
    const float* xb = x + (size_t)b * CIN * PIX_OUT + px0 + sp;

    __shared__ short xs0[32 * 32];      // 2 KiB each
    __shared__ short xs1[32 * 32];

    // LDS layout: row = px (64 B = 32ch bf16), slot swizzle ^((px&3)<<4)
    char* const xw0 = (char*)xs0 + sp * 64 + ((sg * 16) ^ ((sp & 3) << 4));
    char* const xw1 = (char*)xs1 + sp * 64 + ((sg * 16) ^ ((sp & 3) << 4));

    // compute role: wave wv covers px cpx, k-block kb (8 ch)
    const int cpx = wv * 16 + (lane & 15);
    const int kb  = lane >> 4;
    const char* const xr0 = (const char*)xs0 + cpx * 64 + ((kb * 16) ^ ((cpx & 3) << 4));
    const char* const xr1 = (const char*)xs1 + cpx * 64 + ((kb * 16) ^ ((cpx & 3) << 4));

    const short* const wp = wb + (size_t)(lane & 15) * CIN + kb * 8;

    f32x4 acc[6];
#pragma unroll
    for (int f = 0; f < 6; ++f) acc[f] = (f32x4){0.f, 0.f, 0.f, 0.f};

    float v0[8], v1[8];
#pragma unroll
    for (int t = 0; t < 8; ++t) v0[t] = xb[(size_t)(sg * 8 + t) * PIX_OUT];
#pragma unroll
    for (int t = 0; t < 8; ++t) v1[t] = xb[(size_t)(32 + sg * 8 + t) * PIX_OUT];
    {
        bf16x8 pk;
#pragma unroll
        for (int t = 0; t < 8; ++t) pk[t] = f2b(v0[t]);
        *(bf16x8*)xw0 = pk;
    }
    __syncthreads();

#pragma unroll 1
    for (int it2 = 0; it2 < 15; ++it2) {
        const int it = it2 * 2;
        // ---- even half: compute chunk `it` from buf0
        if (it + 2 < 30) {
#pragma unroll
            for (int t = 0; t < 8; ++t)
                v0[t] = xb[(size_t)((it + 2) * 32 + sg * 8 + t) * PIX_OUT];
        }
        {   // pack chunk it+1 (v1) -> buf1
            bf16x8 pk;
#pragma unroll
            for (int t = 0; t < 8; ++t) pk[t] = f2b(v1[t]);
            *(bf16x8*)xw1 = pk;
        }
        {
            const bf16x8 bfrag = *(const bf16x8*)xr0;
#pragma unroll
            for (int f = 0; f < 6; ++f) {
                const bf16x8 afrag = *(const bf16x8*)(wp + (size_t)f * 16 * CIN + it * 32);
                acc[f] = __builtin_amdgcn_mfma_f32_16x16x32_bf16(afrag, bfrag, acc[f], 0, 0, 0);
            }
        }
        __syncthreads();

        // ---- odd half: compute chunk `it+1` from buf1
        if (it + 3 < 30) {
#pragma unroll
            for (int t = 0; t < 8; ++t)
                v1[t] = xb[(size_t)((it + 3) * 32 + sg * 8 + t) * PIX_OUT];
        }
        if (it + 2 < 30) {   // pack chunk it+2 (v0) -> buf0
            bf16x8 pk;
#pragma unroll
            for (int t = 0; t < 8; ++t) pk[t] = f2b(v0[t]);
            *(bf16x8*)xw0 = pk;
        }
        {
            const bf16x8 bfrag = *(const bf16x8*)xr1;
#pragma unroll
            for (int f = 0; f < 6; ++f) {
                const bf16x8 afrag = *(const bf16x8*)(wp + (size_t)f * 16 * CIN + (it + 1) * 32);
                acc[f] = __builtin_amdgcn_mfma_f32_16x16x32_bf16(afrag, bfrag, acc[f], 0, 0, 0);
            }
        }
        __syncthreads();
    }

    // ---- epilogue: C/D layout col(px) = lane&15, row(o) = (lane>>4)*4 + r
    {
        float* yb = y + (size_t)b * COUT * PIX_OUT + px0 + cpx;
#pragma unroll
        for (int f = 0; f < 6; ++f) {
            const int o0 = f * 16 + (lane >> 4) * 4;
#pragma unroll
            for (int r = 0; r < 4; ++r) {
                const int o = o0 + r;
                yb[(size_t)o * PIX_OUT] = acc[f][r] + bias[o];
            }
        }
    }
}

// ---------------------------------------------------------------------------
// Antialiased triangle resize weights for 58 -> 56 on the PADDED grid
// (sf = (o+0.5)*58/56 - 0.5, w_i = relu(1 - |sf-i|*56/58), normalized over
// i in [0,58)). Returned indices are mapped to the 56-grid: clamp(i-1,0,55),
// which reproduces the replicate-padded ring exactly.
__device__ __forceinline__ void rweights56(int o, int* idx, float* wt) {
    const float ratio = 58.0f / 56.0f;
    const float kinv  = 56.0f / 58.0f;
    const float sf = ((float)o + 0.5f) * ratio - 0.5f;
    const int f0 = (int)floorf(sf);
    float sum = 0.f;
#pragma unroll
    for (int t = 0; t < 4; ++t) {
        int i = f0 - 1 + t;
        float w = fmaxf(1.0f - fabsf(sf - (float)i) * kinv, 0.0f);
        if (i < 0 || i > HP - 1) w = 0.0f;
        idx[t] = min(HH - 1, max(0, i - 1));   // 58-grid -> 56-grid
        wt[t] = w;
        sum += w;
    }
    const float inv = 1.0f / sum;
#pragma unroll
    for (int t = 0; t < 4; ++t) wt[t] *= inv;
}

// ---------------------------------------------------------------------------
// K2: out = alpha*(x1+x2+x3)/3 + (1-alpha)*resize(y56). 2 px per thread.
__global__ void finalize(const float* __restrict__ x, const int* __restrict__ pad_hv,
                         const int* __restrict__ idt, const float* __restrict__ y,
                         const float* __restrict__ alpha_p, float* __restrict__ out) {
    const int bc = blockIdx.y;      // b*96 + co
    const int co = bc % COUT;
    const int b  = bc / COUT;
    const int p2 = (blockIdx.x * 256 + threadIdx.x) * 2;
    if (p2 >= PIX_OUT) return;
    const int h = p2 / WW_;
    const int w = p2 - h * WW_;          // even; w+1 in same row
    const float alpha = alpha_p[0];

    const float* xb = x + (size_t)b * CIN * PIX_OUT;

    float a0 = 0.f, a1 = 0.f;
#pragma unroll
    for (int g = 0; g < GG; ++g) {
#pragma unroll
        for (int k = 0; k < NK_; ++k) {
            const int slot = co * NK_ + k;
            const int ic = g * (COUT * NK_) + slot;
            const float* xc = xb + (size_t)ic * PIX_OUT;
            const int sh  = pad_hv[slot * 4 + g];
            const int sv  = pad_hv[slot * 4 + 2 + g];
            const int idm = idt[slot * 2 + g];

            // horizontal shift (w axis), branchless
            const int jw = w + sh;
            const float m0 = (jw >= -1 && jw <= WW_) ? 1.f : 0.f;
            const float m1 = (jw + 1 >= -1 && jw + 1 <= WW_) ? 1.f : 0.f;
            a0 += m0 * xc[h * WW_ + min(WW_ - 1, max(0, jw))];
            a1 += m1 * xc[h * WW_ + min(WW_ - 1, max(0, jw + 1))];

            // vertical shift (h axis): same row for both px -> float2
            const int ih2 = h + sv;
            const float mv = (ih2 >= -1 && ih2 <= HH) ? 1.f : 0.f;
            const float2 vv = *(const float2*)(xc + min(HH - 1, max(0, ih2)) * WW_ + w);
            a0 += mv * vv.x;
            a1 += mv * vv.y;

            // identity slot (uniform branch per block)
            if (idm >= 0) {
                const float2 iv = *(const float2*)(xc + h * WW_ + w);
                a0 += iv.x;
                a1 += iv.y;
            }
        }
    }

    // separable antialiased resize of y56
    int ihx[4], iwa[4], iwb[4];
    float whx[4], wwa[4], wwb[4];
    rweights56(h, ihx, whx);
    rweights56(w, iwa, wwa);
    rweights56(w + 1, iwb, wwb);
    const float* yb = y + (size_t)bc * PIX_OUT;
    float l0 = 0.f, l1 = 0.f;
#pragma unroll
    for (int a = 0; a < 4; ++a) {
        const float* yr = yb + ihx[a] * WW_;
        float r0 = 0.f, r1 = 0.f;
#pragma unroll
        for (int t = 0; t < 4; ++t) {
            r0 = fmaf(wwa[t], yr[iwa[t]], r0);
            r1 = fmaf(wwb[t], yr[iwb[t]], r1);
        }
        l0 = fmaf(whx[a], r0, l0);
        l1 = fmaf(whx[a], r1, l1);
    }

    const float ia = 1.0f - alpha;
    float2 res;
    res.x = alpha * a0 * (1.0f / 3.0f) + ia * l0;
    res.y = alpha * a1 * (1.0f / 3.0f) + ia * l1;
    *(float2*)(out + (size_t)bc * PIX_OUT + p2) = res;
}

// ---------------------------------------------------------------------------
extern "C" void kernel_launch(void* const* d_in, const int* in_sizes, int n_in,
                              void* d_out, int out_size, void* d_ws, size_t ws_size,
                              hipStream_t stream) {
    const float* x      = (const float*)d_in[0];
    const int*   pad_hv = (const int*)d_in[1];
    const int*   idt    = (const int*)d_in[2];
    const float* lsc    = (const float*)d_in[3];
    const float* lbi    = (const float*)d_in[4];
    const float* pw     = (const float*)d_in[5];
    const float* alpha  = (const float*)d_in[6];
    float* out = (float*)d_out;

    float* ws   = (float*)d_ws;
    short* wb   = (short*)(ws + WB_OFF);
    float* bias = ws + BIAS_OFF;
    float* y    = ws + Y_OFF;

    prep_wb<<<(COUT * CIN + 255) / 256, 256, 0, stream>>>(pw, lsc, wb);
    prep_bias<<<1, 128, 0, stream>>>(pw, lbi, bias);
    conv_mfma<<<dim3(PIX_OUT / 32, B_), 128, 0, stream>>>(x, wb, bias, y);
    finalize<<<dim3((PIX_OUT / 2 + 255) / 256, B_ * COUT), 256, 0, stream>>>(
        x, pad_hv, idt, y, alpha, out);
}